// Round 4
// baseline (590.747 us; speedup 1.0000x reference)
//
#include <hip/hip_runtime.h>
#include <hip/hip_bf16.h>

#define H 128
#define H2 132   // padded f32 LDS row stride (breaks 16-way bank conflict on col-slice b128)
#define SQL 50
#define LPROTO 500
#define KTOP 4
#define BQ 1024
#define ITEMS 100000

typedef __attribute__((ext_vector_type(8))) short bf16x8;
typedef __attribute__((ext_vector_type(4))) float f32x4;

__device__ __forceinline__ float wsum(float v){
#pragma unroll
  for (int o = 32; o; o >>= 1) v += __shfl_xor(v, o, 64);
  return v;
}
__device__ __forceinline__ float wmax(float v){
#pragma unroll
  for (int o = 32; o; o >>= 1) v = fmaxf(v, __shfl_xor(v, o, 64));
  return v;
}
__device__ __forceinline__ unsigned short f2bf(float x){
  unsigned int u = __builtin_bit_cast(unsigned int, x);
  unsigned int r = u + 0x7fffu + ((u >> 16) & 1u);
  return (unsigned short)(r >> 16);
}
__device__ __forceinline__ float bf2f(unsigned short h){
  unsigned int u = ((unsigned int)h) << 16;
  return __builtin_bit_cast(float, u);
}

// y = src[0..49][:] @ W; wt_hi/lo bf16 [c][k]; 3-term hi/lo split ~ f32 accuracy.
// 8 waves: wave>>1 = 16-row tile (0..3), wave&1 = 4-wide j half.
__device__ __forceinline__ void mm_mfma(const float (*src)[H2], float (*dst)[H2],
                                        const unsigned short* __restrict__ wt_hi,
                                        const unsigned short* __restrict__ wt_lo,
                                        int lane, int wave)
{
  const int r15 = lane & 15;
  const int g   = lane >> 4;
  const int kof = g * 8;
  const int tile = wave >> 1;
  const int jbase = (wave & 1) * 4;
  const int row = tile * 16 + r15;
  const int srow = (row < SQL) ? row : 0;

  bf16x8 ah[4], al[4];
#pragma unroll
  for (int ks = 0; ks < 4; ks++){
    const float* p = &src[srow][ks * 32 + kof];
    float4 x0 = *reinterpret_cast<const float4*>(p);
    float4 x1 = *reinterpret_cast<const float4*>(p + 4);
    float xs[8] = {x0.x, x0.y, x0.z, x0.w, x1.x, x1.y, x1.z, x1.w};
    bf16x8 h, l;
#pragma unroll
    for (int e = 0; e < 8; e++){
      unsigned short hb = f2bf(xs[e]);
      float rem = xs[e] - bf2f(hb);
      h[e] = (short)hb;
      l[e] = (short)f2bf(rem);
    }
    ah[ks] = h; al[ks] = l;
  }

  f32x4 acc[4];
#pragma unroll
  for (int jj = 0; jj < 4; jj++) acc[jj] = (f32x4){0.f, 0.f, 0.f, 0.f};

#pragma unroll
  for (int jj = 0; jj < 4; jj++){
    int j = jbase + jj;
    const unsigned short* bp = wt_hi + (j * 16 + r15) * H + kof;
    const unsigned short* lp = wt_lo + (j * 16 + r15) * H + kof;
    f32x4 a = acc[jj];
#pragma unroll
    for (int ks = 0; ks < 4; ks++){
      bf16x8 bh = *reinterpret_cast<const bf16x8*>(bp + ks * 32);
      bf16x8 bl = *reinterpret_cast<const bf16x8*>(lp + ks * 32);
      a = __builtin_amdgcn_mfma_f32_16x16x32_bf16(ah[ks], bh, a, 0, 0, 0);
      a = __builtin_amdgcn_mfma_f32_16x16x32_bf16(al[ks], bh, a, 0, 0, 0);
      a = __builtin_amdgcn_mfma_f32_16x16x32_bf16(ah[ks], bl, a, 0, 0, 0);
    }
    acc[jj] = a;
  }

#pragma unroll
  for (int jj = 0; jj < 4; jj++){
    int j = jbase + jj;
#pragma unroll
    for (int r = 0; r < 4; r++){
      int orow = tile * 16 + g * 4 + r;
      if (orow < SQL) dst[orow][j * 16 + r15] = acc[jj][r];
    }
  }
}

// ---------------- per-batch-row pipeline: one block (8 waves) per b ----------------
extern "C" __global__ __launch_bounds__(512)
void sine_row(const float* __restrict__ item_emb, const float* __restrict__ pos_emb,
              const float* __restrict__ proto,
              const float* __restrict__ w2, const float* __restrict__ w5,
              const float* __restrict__ w7,
              const unsigned short* __restrict__ wt,
              const float* __restrict__ ln1g, const float* __restrict__ ln1b,
              const float* __restrict__ ln2g, const float* __restrict__ ln2b,
              const float* __restrict__ ln3g, const float* __restrict__ ln3b,
              const float* __restrict__ ln4g, const float* __restrict__ ln4b,
              const int* __restrict__ seq,
              unsigned short* __restrict__ finalbf)
{
  __shared__ __align__(16) float sA[SQL][H2];
  __shared__ __align__(16) float sE[SQL][H2];
  __shared__ __align__(16) float scp[KTOP][H];
  __shared__ __align__(16) float slncp[KTOP][H];
  __shared__ __align__(16) float sintr[KTOP][H];
  __shared__ __align__(16) float svcv[H];
  __shared__ __align__(16) float scapt[H];
  __shared__ float srow[SQL];
  __shared__ float smask[SQL];
  __shared__ float spkt[SQL][KTOP];
  __shared__ float sak[SQL][KTOP];
  __shared__ float ssc[LPROTO];
  __shared__ float schs[KTOP];
  __shared__ int   srank[KTOP];
  __shared__ float sesc[KTOP];

  const int b = blockIdx.x;
  const int t = threadIdx.x;
  const int lane = t & 63;
  const int wave = t >> 6;
  const int* sq = seq + b * SQL;

  const unsigned short* w1t_hi = wt;
  const unsigned short* w1t_lo = wt + 16384;
  const unsigned short* w3t_hi = wt + 32768;
  const unsigned short* w3t_lo = wt + 49152;
  const unsigned short* w4t_hi = wt + 65536;
  const unsigned short* w4t_lo = wt + 81920;
  const unsigned short* w6t_hi = wt + 98304;
  const unsigned short* w6t_lo = wt + 114688;

  // phase 0: mask + gather ie
  if (t < SQL) smask[t] = (sq[t] != 0) ? 1.0f : 0.0f;
  for (int c = t; c < SQL * (H / 4); c += 512){
    int s = c >> 5, q = c & 31;
    int idx = sq[s];
    float4 v = reinterpret_cast<const float4*>(item_emb)[idx * (H / 4) + q];
    reinterpret_cast<float4*>(&sA[s][0])[q] = v;
  }
  __syncthreads();

  // phase 1: y = ie@w1 -> sE ; sa_score = tanh(y)@w2 - (1-mask)*1e4
  mm_mfma(sA, sE, w1t_hi, w1t_lo, lane, wave);
  __syncthreads();
  for (int s = wave; s < SQL; s += 8){
    float y0 = sE[s][lane], y1 = sE[s][64 + lane];
    float part = tanhf(y0) * w2[lane] + tanhf(y1) * w2[64 + lane];
    float sc = wsum(part);
    if (lane == 0) srow[s] = sc - (1.0f - smask[s]) * 10000.0f;
  }
  __syncthreads();

  // phase 2: alpha = softmax(sa_score); vcv = alpha @ ie
  if (wave == 0){
    float v = (lane < SQL) ? srow[lane] : -1e30f;
    float m = wmax(v);
    float e = (lane < SQL) ? expf(v - m) : 0.0f;
    float sum = wsum(e);
    if (lane < SQL) srow[lane] = e / sum;
  }
  __syncthreads();
  if (t < H){
    float acc = 0.f;
    for (int s = 0; s < SQL; s++) acc = fmaf(srow[s], sA[s][t], acc);
    svcv[t] = acc;
  }
  __syncthreads();

  // phase 3: proto scores + stable top-4
  for (int l = t; l < LPROTO; l += 512){
    const float4* pr = reinterpret_cast<const float4*>(proto + l * H);
    const float4* vc = reinterpret_cast<const float4*>(svcv);
    float acc = 0.f;
    for (int q = 0; q < H / 4; q++){
      float4 p = pr[q], v = vc[q];
      acc += p.x * v.x + p.y * v.y + p.z * v.z + p.w * v.w;
    }
    ssc[l] = acc;
  }
  __syncthreads();
  if (wave == 0){
    float cand[8];
#pragma unroll
    for (int i = 0; i < 8; i++){
      int l = lane + 64 * i;
      cand[i] = (l < LPROTO) ? ssc[l] : -1e30f;
    }
    for (int k = 0; k < KTOP; k++){
      float bv = -1e30f; int bi = 0x7fffffff;
#pragma unroll
      for (int i = 0; i < 8; i++){
        int l = lane + 64 * i;
        if (cand[i] > bv || (cand[i] == bv && l < bi)){ bv = cand[i]; bi = l; }
      }
#pragma unroll
      for (int o = 32; o; o >>= 1){
        float ov = __shfl_xor(bv, o, 64);
        int   oi = __shfl_xor(bi, o, 64);
        if (ov > bv || (ov == bv && oi < bi)){ bv = ov; bi = oi; }
      }
      if (lane == 0){ schs[k] = bv; srank[k] = bi; }
      int li = bi - lane;
#pragma unroll
      for (int i = 0; i < 8; i++) if (64 * i == li) cand[i] = -1e30f;
    }
  }
  __syncthreads();
  if (wave < KTOP){
    int k = wave;
    int r = srank[k];
    float sg = 1.0f / (1.0f + expf(-schs[k]));
    float v0 = sg * proto[r * H + lane];
    float v1 = sg * proto[r * H + 64 + lane];
    float mu = wsum(v0 + v1) * (1.0f / H);
    float d0 = v0 - mu, d1 = v1 - mu;
    float var = wsum(d0 * d0 + d1 * d1) * (1.0f / H);
    float rs = rsqrtf(var + 1e-5f);
    scp[k][lane] = v0; scp[k][64 + lane] = v1;
    slncp[k][lane]      = d0 * rs * ln2g[lane]      + ln2b[lane];
    slncp[k][64 + lane] = d1 * rs * ln2g[64 + lane] + ln2b[64 + lane];
  }
  __syncthreads();

  // phase 5: y = ie@w3 -> sE ; p_kt = softmax_k(ln1(y).ln2cp)*mask
  mm_mfma(sA, sE, w3t_hi, w3t_lo, lane, wave);
  __syncthreads();
  for (int s = wave; s < SQL; s += 8){
    float a0 = sE[s][lane], a1 = sE[s][64 + lane];
    float mu = wsum(a0 + a1) * (1.0f / H);
    float d0 = a0 - mu, d1 = a1 - mu;
    float var = wsum(d0 * d0 + d1 * d1) * (1.0f / H);
    float rs = rsqrtf(var + 1e-5f);
    float l0 = d0 * rs * ln1g[lane]      + ln1b[lane];
    float l1 = d1 * rs * ln1g[64 + lane] + ln1b[64 + lane];
    float sc0 = wsum(l0 * slncp[0][lane] + l1 * slncp[0][64 + lane]);
    float sc1 = wsum(l0 * slncp[1][lane] + l1 * slncp[1][64 + lane]);
    float sc2 = wsum(l0 * slncp[2][lane] + l1 * slncp[2][64 + lane]);
    float sc3 = wsum(l0 * slncp[3][lane] + l1 * slncp[3][64 + lane]);
    float m = fmaxf(fmaxf(sc0, sc1), fmaxf(sc2, sc3));
    float e0 = expf(sc0 - m), e1 = expf(sc1 - m), e2 = expf(sc2 - m), e3 = expf(sc3 - m);
    float inv = 1.0f / (e0 + e1 + e2 + e3);
    float msk = smask[s];
    if (lane == 0){
      spkt[s][0] = e0 * inv * msk; spkt[s][1] = e1 * inv * msk;
      spkt[s][2] = e2 * inv * msk; spkt[s][3] = e3 * inv * msk;
    }
  }
  __syncthreads();

  // phase 4: emb = pos_emb[50-s] + ie -> sE
  for (int c = t; c < SQL * (H / 4); c += 512){
    int s = c >> 5, q = c & 31;
    float4 pv = reinterpret_cast<const float4*>(pos_emb + (SQL - s) * H)[q];
    float4 iv = reinterpret_cast<float4*>(&sA[s][0])[q];
    float4 r; r.x = pv.x + iv.x; r.y = pv.y + iv.y; r.z = pv.z + iv.z; r.w = pv.w + iv.w;
    reinterpret_cast<float4*>(&sE[s][0])[q] = r;
  }
  __syncthreads();

  // phase 6: y = emb@w4 -> sA ; a_k_score = tanh(y)@w5
  mm_mfma(sE, sA, w4t_hi, w4t_lo, lane, wave);
  __syncthreads();
  for (int s = wave; s < SQL; s += 8){
    float t0 = tanhf(sA[s][lane]), t1 = tanhf(sA[s][64 + lane]);
    float s0 = wsum(t0 * w5[lane * 4 + 0] + t1 * w5[(64 + lane) * 4 + 0]);
    float s1 = wsum(t0 * w5[lane * 4 + 1] + t1 * w5[(64 + lane) * 4 + 1]);
    float s2 = wsum(t0 * w5[lane * 4 + 2] + t1 * w5[(64 + lane) * 4 + 2]);
    float s3 = wsum(t0 * w5[lane * 4 + 3] + t1 * w5[(64 + lane) * 4 + 3]);
    if (lane == 0){ sak[s][0] = s0; sak[s][1] = s1; sak[s][2] = s2; sak[s][3] = s3; }
  }
  __syncthreads();

  // phase 7: a_k = softmax_over_s * mask ; p = p_kt * a_k
  if (wave < KTOP){
    int k = wave;
    float v = (lane < SQL) ? sak[lane][k] : -1e30f;
    float m = wmax(v);
    float e = (lane < SQL) ? expf(v - m) : 0.0f;
    float sum = wsum(e);
    if (lane < SQL) sak[lane][k] = (e / sum) * smask[lane] * spkt[lane][k];
  }
  __syncthreads();

  // phase 8: interesting[k] = ln3( sum_s p[s][k] * emb[s] )
  for (int c = t; c < KTOP * H; c += 512){
    int k = c >> 7, h = c & 127;
    float acc = 0.f;
    for (int s = 0; s < SQL; s++) acc = fmaf(sak[s][k], sE[s][h], acc);
    sintr[k][h] = acc;
  }
  __syncthreads();
  if (wave < KTOP){
    int k = wave;
    float v0 = sintr[k][lane], v1 = sintr[k][64 + lane];
    float mu = wsum(v0 + v1) * (1.0f / H);
    float d0 = v0 - mu, d1 = v1 - mu;
    float var = wsum(d0 * d0 + d1 * d1) * (1.0f / H);
    float rs = rsqrtf(var + 1e-5f);
    sintr[k][lane]      = d0 * rs * ln3g[lane]      + ln3b[lane];
    sintr[k][64 + lane] = d1 * rs * ln3g[64 + lane] + ln3b[64 + lane];
  }
  __syncthreads();

  // phase 9: xu = p_kt @ chosen_proto -> sA ; y = xu@w6 -> sE ; c_score
  for (int c = t; c < SQL * H; c += 512){
    int s = c >> 7, h = c & 127;
    float acc = spkt[s][0] * scp[0][h] + spkt[s][1] * scp[1][h]
              + spkt[s][2] * scp[2][h] + spkt[s][3] * scp[3][h];
    sA[s][h] = acc;
  }
  __syncthreads();
  mm_mfma(sA, sE, w6t_hi, w6t_lo, lane, wave);
  __syncthreads();
  for (int s = wave; s < SQL; s += 8){
    float part = tanhf(sE[s][lane]) * w7[lane] + tanhf(sE[s][64 + lane]) * w7[64 + lane];
    float sc = wsum(part);
    if (lane == 0) srow[s] = sc - (1.0f - smask[s]) * 10000.0f;
  }
  __syncthreads();

  // phase 10: c_w = softmax(c_score); c_apt = ln4(c_w @ xu)
  if (wave == 0){
    float v = (lane < SQL) ? srow[lane] : -1e30f;
    float m = wmax(v);
    float e = (lane < SQL) ? expf(v - m) : 0.0f;
    float sum = wsum(e);
    if (lane < SQL) srow[lane] = e / sum;
  }
  __syncthreads();
  if (t < H){
    float acc = 0.f;
    for (int s = 0; s < SQL; s++) acc = fmaf(srow[s], sA[s][t], acc);
    scapt[t] = acc;
  }
  __syncthreads();
  if (wave == 0){
    float v0 = scapt[lane], v1 = scapt[64 + lane];
    float mu = wsum(v0 + v1) * (1.0f / H);
    float d0 = v0 - mu, d1 = v1 - mu;
    float var = wsum(d0 * d0 + d1 * d1) * (1.0f / H);
    float rs = rsqrtf(var + 1e-5f);
    scapt[lane]      = d0 * rs * ln4g[lane]      + ln4b[lane];
    scapt[64 + lane] = d1 * rs * ln4g[64 + lane] + ln4b[64 + lane];
  }
  __syncthreads();

  // phase 11: e = softmax(e_score/0.1); final = e @ interesting (bf16)
  if (wave < KTOP){
    int k = wave;
    float part = scapt[lane] * sintr[k][lane] + scapt[64 + lane] * sintr[k][64 + lane];
    float sc = wsum(part);
    if (lane == 0) sesc[k] = sc;
  }
  __syncthreads();
  if (t < H){
    float e0 = sesc[0] * 10.0f, e1 = sesc[1] * 10.0f, e2 = sesc[2] * 10.0f, e3 = sesc[3] * 10.0f;
    float m = fmaxf(fmaxf(e0, e1), fmaxf(e2, e3));
    float x0 = expf(e0 - m), x1 = expf(e1 - m), x2 = expf(e2 - m), x3 = expf(e3 - m);
    float inv = 1.0f / (x0 + x1 + x2 + x3);
    float f = (x0 * sintr[0][t] + x1 * sintr[1][t] + x2 * sintr[2][t] + x3 * sintr[3][t]) * inv;
    finalbf[b * H + t] = f2bf(f);
  }
}

// ---------------- weight prep ----------------
extern "C" __global__ void wprep(const float* __restrict__ w1, const float* __restrict__ w3,
                                 const float* __restrict__ w4, const float* __restrict__ w6,
                                 unsigned short* __restrict__ out){
  const float* srcs[4] = {w1, w3, w4, w6};
  const float* src = srcs[blockIdx.x];
  unsigned short* hi = out + blockIdx.x * 32768;
  unsigned short* lo = hi + 16384;
  for (int i = threadIdx.x; i < 16384; i += 256){
    int c = i >> 7, k = i & 127;
    float f = src[k * H + c];
    unsigned short h = f2bf(f);
    hi[i] = h;
    lo[i] = f2bf(f - bf2f(h));
  }
}

// ---------------- item_emb f32 -> bf16 ----------------
extern "C" __global__ void conv_bf16(const float* __restrict__ in,
                                     unsigned short* __restrict__ out, int n4){
  int i = blockIdx.x * blockDim.x + threadIdx.x;
  int stride = gridDim.x * blockDim.x;
  for (; i < n4; i += stride){
    float4 v = reinterpret_cast<const float4*>(in)[i];
    union { unsigned short u[4]; uint2 v2; } o;
    o.u[0] = f2bf(v.x); o.u[1] = f2bf(v.y); o.u[2] = f2bf(v.z); o.u[3] = f2bf(v.w);
    reinterpret_cast<uint2*>(out)[i] = o.v2;
  }
}

// ---------------- scores: LDS-free MFMA, items as A-operand, x4 stores ----------------
// block = 64 items x 256 batch; wave = 16 items x 256 batch; acc = 16 x f32x4
extern "C" __global__ __launch_bounds__(256)
void gemm_scores(const unsigned short* __restrict__ Bm,   // items [100000][128] bf16
                 const unsigned short* __restrict__ A,    // final [1024][128] bf16
                 float* __restrict__ C)
{
  const int lane = threadIdx.x & 63, wave = threadIdx.x >> 6;
  const int r15 = lane & 15, g = lane >> 4;
  const int nb = blockIdx.x * 64 + wave * 16;     // item tile base (this wave)
  const int m0 = blockIdx.y * 256;                // batch base

  const int irow = nb + r15;
  const int it = (irow < ITEMS) ? irow : 0;
  bf16x8 af[4];
#pragma unroll
  for (int ks = 0; ks < 4; ks++)
    af[ks] = *reinterpret_cast<const bf16x8*>(Bm + (size_t)it * H + ks * 32 + g * 8);

  f32x4 acc[16];
#pragma unroll
  for (int j = 0; j < 16; j++) acc[j] = (f32x4){0.f, 0.f, 0.f, 0.f};

#pragma unroll
  for (int j = 0; j < 16; j++){
    const unsigned short* fp = A + (m0 + j * 16 + r15) * H + g * 8;
    f32x4 a = acc[j];
#pragma unroll
    for (int ks = 0; ks < 4; ks++){
      bf16x8 bf = *reinterpret_cast<const bf16x8*>(fp + ks * 32);
      a = __builtin_amdgcn_mfma_f32_16x16x32_bf16(af[ks], bf, a, 0, 0, 0);
    }
    acc[j] = a;
  }

  const int n = nb + g * 4;                       // 4 consecutive item columns per lane
  if (n < ITEMS){
#pragma unroll
    for (int j = 0; j < 16; j++){
      int m = m0 + j * 16 + r15;
      *reinterpret_cast<f32x4*>(C + (size_t)m * ITEMS + n) = acc[j];
    }
  }
}

// ---------------- prototype covariance regularizer ----------------
extern "C" __global__ void proto_mean(const float* __restrict__ proto,
                                      float* __restrict__ mean, float* __restrict__ accum){
  int h = threadIdx.x;
  if (h < 2) accum[h] = 0.0f;
  float acc = 0.f;
  for (int l = 0; l < LPROTO; l++) acc += proto[l * H + h];
  mean[h] = acc * (1.0f / LPROTO);
}

extern "C" __global__ __launch_bounds__(256)
void proto_cov(const float* __restrict__ proto, const float* __restrict__ mean,
               float* __restrict__ accum){
  __shared__ float ci[H];
  __shared__ float red[256];
  int i = blockIdx.x, t = threadIdx.x;
  if (t < H) ci[t] = proto[i * H + t] - mean[t];
  __syncthreads();
  float total = 0.f;
  for (int j = t; j < LPROTO; j += 256){
    float acc = 0.f;
    for (int h = 0; h < H; h++) acc = fmaf(ci[h], proto[j * H + h] - mean[h], acc);
    float m = acc * (1.0f / H);
    total += m * m;
    if (j == i) atomicAdd(&accum[1], m * m);
  }
  red[t] = total; __syncthreads();
  for (int o = 128; o; o >>= 1){ if (t < o) red[t] += red[t + o]; __syncthreads(); }
  if (t == 0) atomicAdd(&accum[0], red[0]);
}

extern "C" __global__ void lc_final(const float* __restrict__ accum, float* __restrict__ out){
  out[(size_t)BQ * ITEMS] = 0.1f * 0.5f * (sqrtf(accum[0]) - sqrtf(accum[1]));
}

// ---------------- launch ----------------
extern "C" void kernel_launch(void* const* d_in, const int* in_sizes, int n_in,
                              void* d_out, int out_size, void* d_ws, size_t ws_size,
                              hipStream_t stream){
  const float* item  = (const float*)d_in[0];
  const float* pos   = (const float*)d_in[1];
  const float* proto = (const float*)d_in[2];
  const float* w1 = (const float*)d_in[3];
  const float* w2 = (const float*)d_in[4];
  const float* w3 = (const float*)d_in[5];
  const float* w4 = (const float*)d_in[6];
  const float* w5 = (const float*)d_in[7];
  const float* w6 = (const float*)d_in[8];
  const float* w7 = (const float*)d_in[9];
  const float* ln1g = (const float*)d_in[10];
  const float* ln1b = (const float*)d_in[11];
  const float* ln2g = (const float*)d_in[12];
  const float* ln2b = (const float*)d_in[13];
  const float* ln3g = (const float*)d_in[14];
  const float* ln3b = (const float*)d_in[15];
  const float* ln4g = (const float*)d_in[16];
  const float* ln4b = (const float*)d_in[17];
  const int* seq = (const int*)d_in[18];
  float* out = (float*)d_out;

  char* ws = (char*)d_ws;
  float* accum = (float*)ws;
  float* mean  = (float*)(ws + 256);
  unsigned short* finalbf = (unsigned short*)(ws + 1024);
  unsigned short* itembf  = (unsigned short*)(ws + 263168);
  unsigned short* wtbuf   = (unsigned short*)(ws + 25863168);

  wprep<<<4, 256, 0, stream>>>(w1, w3, w4, w6, wtbuf);
  conv_bf16<<<2048, 256, 0, stream>>>(item, itembf, ITEMS * H / 4);

  sine_row<<<BQ, 512, 0, stream>>>(item, pos, proto, w2, w5, w7, wtbuf,
                                   ln1g, ln1b, ln2g, ln2b, ln3g, ln3b, ln4g, ln4b,
                                   seq, finalbf);

  gemm_scores<<<dim3((ITEMS + 63) / 64, BQ / 256), 256, 0, stream>>>(itembf, finalbf, out);

  proto_mean<<<1, 128, 0, stream>>>(proto, mean, accum);
  proto_cov<<<LPROTO, 256, 0, stream>>>(proto, mean, accum);
  lc_final<<<1, 1, 0, stream>>>(accum, out);
}

// Round 5
// 378.907 us; speedup vs baseline: 1.5591x; 1.5591x over previous
//
#include <hip/hip_runtime.h>
#include <hip/hip_bf16.h>

#define H 128
#define H2 132   // padded f32 LDS row stride
#define SQL 50
#define LPROTO 500
#define KTOP 4
#define BQ 1024
#define ITEMS 100000

typedef __attribute__((ext_vector_type(8))) short bf16x8;
typedef __attribute__((ext_vector_type(4))) float f32x4;

__device__ __forceinline__ float wsum(float v){
#pragma unroll
  for (int o = 32; o; o >>= 1) v += __shfl_xor(v, o, 64);
  return v;
}
__device__ __forceinline__ float wmax(float v){
#pragma unroll
  for (int o = 32; o; o >>= 1) v = fmaxf(v, __shfl_xor(v, o, 64));
  return v;
}
// 16-lane-group sum (stays within lanes sharing lane>>4)
__device__ __forceinline__ float gr16(float v){
  v += __shfl_xor(v, 1, 64);
  v += __shfl_xor(v, 2, 64);
  v += __shfl_xor(v, 4, 64);
  v += __shfl_xor(v, 8, 64);
  return v;
}
__device__ __forceinline__ unsigned short f2bf(float x){
  unsigned int u = __builtin_bit_cast(unsigned int, x);
  unsigned int r = u + 0x7fffu + ((u >> 16) & 1u);
  return (unsigned short)(r >> 16);
}
__device__ __forceinline__ float bf2f(unsigned short h){
  unsigned int u = ((unsigned int)h) << 16;
  return __builtin_bit_cast(float, u);
}

// acc[j][r] = (src @ W)[wave*16 + g*4 + r][j*16 + r15]; 3-term hi/lo bf16 split.
__device__ __forceinline__ void mm_acc(const float (*src)[H2],
                                       const unsigned short* __restrict__ wt_hi,
                                       const unsigned short* __restrict__ wt_lo,
                                       int lane, int wave, f32x4* acc)
{
  const int r15 = lane & 15;
  const int g   = lane >> 4;
  const int kof = g * 8;
  const int row = wave * 16 + r15;
  const int srw = (row < SQL) ? row : 0;

  bf16x8 ah[4], al[4];
#pragma unroll
  for (int ks = 0; ks < 4; ks++){
    const float* p = &src[srw][ks * 32 + kof];
    float4 x0 = *reinterpret_cast<const float4*>(p);
    float4 x1 = *reinterpret_cast<const float4*>(p + 4);
    float xs[8] = {x0.x, x0.y, x0.z, x0.w, x1.x, x1.y, x1.z, x1.w};
    bf16x8 h, l;
#pragma unroll
    for (int e = 0; e < 8; e++){
      unsigned short hb = f2bf(xs[e]);
      float rem = xs[e] - bf2f(hb);
      h[e] = (short)hb;
      l[e] = (short)f2bf(rem);
    }
    ah[ks] = h; al[ks] = l;
  }

#pragma unroll
  for (int j = 0; j < 8; j++){
    acc[j] = (f32x4){0.f, 0.f, 0.f, 0.f};
    const unsigned short* bp = wt_hi + (j * 16 + r15) * H + kof;
    const unsigned short* lp = wt_lo + (j * 16 + r15) * H + kof;
    f32x4 a = acc[j];
#pragma unroll
    for (int ks = 0; ks < 4; ks++){
      bf16x8 bh = *reinterpret_cast<const bf16x8*>(bp + ks * 32);
      bf16x8 bl = *reinterpret_cast<const bf16x8*>(lp + ks * 32);
      a = __builtin_amdgcn_mfma_f32_16x16x32_bf16(ah[ks], bh, a, 0, 0, 0);
      a = __builtin_amdgcn_mfma_f32_16x16x32_bf16(al[ks], bh, a, 0, 0, 0);
      a = __builtin_amdgcn_mfma_f32_16x16x32_bf16(ah[ks], bl, a, 0, 0, 0);
    }
    acc[j] = a;
  }
}

// ---------------- per-batch-row pipeline: one block (4 waves) per b ----------------
extern "C" __global__ __launch_bounds__(256)
void sine_row(const float* __restrict__ item_emb, const float* __restrict__ pos_emb,
              const float* __restrict__ proto,
              const float* __restrict__ w2, const float* __restrict__ w5,
              const float* __restrict__ w7,
              const unsigned short* __restrict__ wt,
              const float* __restrict__ ln1g, const float* __restrict__ ln1b,
              const float* __restrict__ ln2g, const float* __restrict__ ln2b,
              const float* __restrict__ ln3g, const float* __restrict__ ln3b,
              const float* __restrict__ ln4g, const float* __restrict__ ln4b,
              const int* __restrict__ seq,
              unsigned short* __restrict__ finalbf)
{
  __shared__ __align__(16) float sA[SQL][H2];     // ie -> xu
  __shared__ __align__(16) float sE[SQL][H2];     // emb
  __shared__ __align__(16) float scp[KTOP][H];
  __shared__ __align__(16) float slncp[KTOP][H];
  __shared__ __align__(16) float sintr[KTOP][H];
  __shared__ __align__(16) float svcv[H];
  __shared__ __align__(16) float scapt[H];
  __shared__ float srow[SQL];
  __shared__ float smask[SQL];
  __shared__ float spkt[SQL][KTOP];
  __shared__ float sak[SQL][KTOP];
  __shared__ float ssc[LPROTO];
  __shared__ float schs[KTOP];
  __shared__ int   srank[KTOP];
  __shared__ float sesc[KTOP];

  const int b = blockIdx.x;
  const int t = threadIdx.x;
  const int lane = t & 63;
  const int wave = t >> 6;
  const int r15 = lane & 15;
  const int g   = lane >> 4;
  const int* sq = seq + b * SQL;

  const unsigned short* w1t_hi = wt;
  const unsigned short* w1t_lo = wt + 16384;
  const unsigned short* w3t_hi = wt + 32768;
  const unsigned short* w3t_lo = wt + 49152;
  const unsigned short* w4t_hi = wt + 65536;
  const unsigned short* w4t_lo = wt + 81920;
  const unsigned short* w6t_hi = wt + 98304;
  const unsigned short* w6t_lo = wt + 114688;

  // phase 0: mask + gather ie
  if (t < SQL) smask[t] = (sq[t] != 0) ? 1.0f : 0.0f;
  for (int c = t; c < SQL * (H / 4); c += 256){
    int s = c >> 5, q = c & 31;
    int idx = sq[s];
    float4 v = reinterpret_cast<const float4*>(item_emb)[idx * (H / 4) + q];
    reinterpret_cast<float4*>(&sA[s][0])[q] = v;
  }
  __syncthreads();

  // phase 1 (fused): sa_score = tanh(ie@w1)@w2 - (1-mask)*1e4
  {
    f32x4 acc[8];
    mm_acc(sA, w1t_hi, w1t_lo, lane, wave, acc);
    float p0 = 0.f, p1 = 0.f, p2 = 0.f, p3 = 0.f;
#pragma unroll
    for (int j = 0; j < 8; j++){
      float w2c = w2[j * 16 + r15];
      p0 = fmaf(tanhf(acc[j][0]), w2c, p0);
      p1 = fmaf(tanhf(acc[j][1]), w2c, p1);
      p2 = fmaf(tanhf(acc[j][2]), w2c, p2);
      p3 = fmaf(tanhf(acc[j][3]), w2c, p3);
    }
    p0 = gr16(p0); p1 = gr16(p1); p2 = gr16(p2); p3 = gr16(p3);
    if (r15 == 0){
      float pv[4] = {p0, p1, p2, p3};
#pragma unroll
      for (int r = 0; r < 4; r++){
        int orow = wave * 16 + g * 4 + r;
        if (orow < SQL) srow[orow] = pv[r] - (1.0f - smask[orow]) * 10000.0f;
      }
    }
  }
  __syncthreads();

  // phase 2: alpha = softmax(sa_score); vcv = alpha @ ie
  if (wave == 0){
    float v = (lane < SQL) ? srow[lane] : -1e30f;
    float m = wmax(v);
    float e = (lane < SQL) ? expf(v - m) : 0.0f;
    float sum = wsum(e);
    if (lane < SQL) srow[lane] = e / sum;
  }
  __syncthreads();
  if (t < H){
    float acc = 0.f;
    for (int s = 0; s < SQL; s++) acc = fmaf(srow[s], sA[s][t], acc);
    svcv[t] = acc;
  }
  __syncthreads();

  // phase 3: proto scores + stable top-4 + chosen/ln2 protos
  for (int l = t; l < LPROTO; l += 256){
    const float4* pr = reinterpret_cast<const float4*>(proto + l * H);
    const float4* vc = reinterpret_cast<const float4*>(svcv);
    float acc = 0.f;
    for (int q = 0; q < H / 4; q++){
      float4 p = pr[q], v = vc[q];
      acc += p.x * v.x + p.y * v.y + p.z * v.z + p.w * v.w;
    }
    ssc[l] = acc;
  }
  __syncthreads();
  if (wave == 0){
    float cand[8];
#pragma unroll
    for (int i = 0; i < 8; i++){
      int l = lane + 64 * i;
      cand[i] = (l < LPROTO) ? ssc[l] : -1e30f;
    }
    for (int k = 0; k < KTOP; k++){
      float bv = -1e30f; int bi = 0x7fffffff;
#pragma unroll
      for (int i = 0; i < 8; i++){
        int l = lane + 64 * i;
        if (cand[i] > bv || (cand[i] == bv && l < bi)){ bv = cand[i]; bi = l; }
      }
#pragma unroll
      for (int o = 32; o; o >>= 1){
        float ov = __shfl_xor(bv, o, 64);
        int   oi = __shfl_xor(bi, o, 64);
        if (ov > bv || (ov == bv && oi < bi)){ bv = ov; bi = oi; }
      }
      if (lane == 0){ schs[k] = bv; srank[k] = bi; }
      int li = bi - lane;
#pragma unroll
      for (int i = 0; i < 8; i++) if (64 * i == li) cand[i] = -1e30f;
    }
  }
  __syncthreads();
  {
    int k = wave;
    int r = srank[k];
    float sg = 1.0f / (1.0f + expf(-schs[k]));
    float v0 = sg * proto[r * H + lane];
    float v1 = sg * proto[r * H + 64 + lane];
    float mu = wsum(v0 + v1) * (1.0f / H);
    float d0 = v0 - mu, d1 = v1 - mu;
    float var = wsum(d0 * d0 + d1 * d1) * (1.0f / H);
    float rs = rsqrtf(var + 1e-5f);
    scp[k][lane] = v0; scp[k][64 + lane] = v1;
    slncp[k][lane]      = d0 * rs * ln2g[lane]      + ln2b[lane];
    slncp[k][64 + lane] = d1 * rs * ln2g[64 + lane] + ln2b[64 + lane];
  }
  __syncthreads();

  // phase 5 (fused): p_kt = softmax_k( ln1(ie@w3) . ln2cp ) * mask
  {
    f32x4 acc[8];
    mm_acc(sA, w3t_hi, w3t_lo, lane, wave, acc);
    // two-pass LN over the 128 cols (8 regs x 16 lanes)
    float s0 = 0.f, s1 = 0.f, s2 = 0.f, s3 = 0.f;
#pragma unroll
    for (int j = 0; j < 8; j++){ s0 += acc[j][0]; s1 += acc[j][1]; s2 += acc[j][2]; s3 += acc[j][3]; }
    float mu0 = gr16(s0) * (1.0f / H), mu1 = gr16(s1) * (1.0f / H);
    float mu2 = gr16(s2) * (1.0f / H), mu3 = gr16(s3) * (1.0f / H);
    float q0 = 0.f, q1 = 0.f, q2 = 0.f, q3 = 0.f;
#pragma unroll
    for (int j = 0; j < 8; j++){
      float d0 = acc[j][0] - mu0, d1 = acc[j][1] - mu1;
      float d2 = acc[j][2] - mu2, d3 = acc[j][3] - mu3;
      q0 = fmaf(d0, d0, q0); q1 = fmaf(d1, d1, q1);
      q2 = fmaf(d2, d2, q2); q3 = fmaf(d3, d3, q3);
    }
    float rs0 = rsqrtf(gr16(q0) * (1.0f / H) + 1e-5f);
    float rs1 = rsqrtf(gr16(q1) * (1.0f / H) + 1e-5f);
    float rs2 = rsqrtf(gr16(q2) * (1.0f / H) + 1e-5f);
    float rs3 = rsqrtf(gr16(q3) * (1.0f / H) + 1e-5f);
    float pk[4][4];
#pragma unroll
    for (int k = 0; k < 4; k++)
#pragma unroll
      for (int r = 0; r < 4; r++) pk[k][r] = 0.f;
#pragma unroll
    for (int j = 0; j < 8; j++){
      int c = j * 16 + r15;
      float gg = ln1g[c], bb = ln1b[c];
      float l0 = fmaf((acc[j][0] - mu0) * rs0, gg, bb);
      float l1 = fmaf((acc[j][1] - mu1) * rs1, gg, bb);
      float l2 = fmaf((acc[j][2] - mu2) * rs2, gg, bb);
      float l3 = fmaf((acc[j][3] - mu3) * rs3, gg, bb);
#pragma unroll
      for (int k = 0; k < 4; k++){
        float w = slncp[k][c];
        pk[k][0] = fmaf(l0, w, pk[k][0]);
        pk[k][1] = fmaf(l1, w, pk[k][1]);
        pk[k][2] = fmaf(l2, w, pk[k][2]);
        pk[k][3] = fmaf(l3, w, pk[k][3]);
      }
    }
#pragma unroll
    for (int k = 0; k < 4; k++)
#pragma unroll
      for (int r = 0; r < 4; r++) pk[k][r] = gr16(pk[k][r]);
    if (r15 == 0){
#pragma unroll
      for (int r = 0; r < 4; r++){
        int orow = wave * 16 + g * 4 + r;
        if (orow < SQL){
          float m = fmaxf(fmaxf(pk[0][r], pk[1][r]), fmaxf(pk[2][r], pk[3][r]));
          float e0 = expf(pk[0][r] - m), e1 = expf(pk[1][r] - m);
          float e2 = expf(pk[2][r] - m), e3 = expf(pk[3][r] - m);
          float inv = 1.0f / (e0 + e1 + e2 + e3);
          float msk = smask[orow];
          spkt[orow][0] = e0 * inv * msk; spkt[orow][1] = e1 * inv * msk;
          spkt[orow][2] = e2 * inv * msk; spkt[orow][3] = e3 * inv * msk;
        }
      }
    }
  }
  // phase 4 (same region, no barrier needed: reads sA, writes sE only): emb = pos + ie
  for (int c = t; c < SQL * (H / 4); c += 256){
    int s = c >> 5, q = c & 31;
    float4 pv = reinterpret_cast<const float4*>(pos_emb + (SQL - s) * H)[q];
    float4 iv = reinterpret_cast<float4*>(&sA[s][0])[q];
    float4 r; r.x = pv.x + iv.x; r.y = pv.y + iv.y; r.z = pv.z + iv.z; r.w = pv.w + iv.w;
    reinterpret_cast<float4*>(&sE[s][0])[q] = r;
  }
  __syncthreads();

  // phase 6 (fused): a_k_score[s][k] = tanh(emb@w4)@w5
  {
    f32x4 acc[8];
    mm_acc(sE, w4t_hi, w4t_lo, lane, wave, acc);
    float pk[4][4];
#pragma unroll
    for (int k = 0; k < 4; k++)
#pragma unroll
      for (int r = 0; r < 4; r++) pk[k][r] = 0.f;
#pragma unroll
    for (int j = 0; j < 8; j++){
      int c = j * 16 + r15;
      float4 w5c = *reinterpret_cast<const float4*>(w5 + c * 4);
      float t0 = tanhf(acc[j][0]), t1 = tanhf(acc[j][1]);
      float t2 = tanhf(acc[j][2]), t3 = tanhf(acc[j][3]);
      pk[0][0] = fmaf(t0, w5c.x, pk[0][0]); pk[0][1] = fmaf(t1, w5c.x, pk[0][1]);
      pk[0][2] = fmaf(t2, w5c.x, pk[0][2]); pk[0][3] = fmaf(t3, w5c.x, pk[0][3]);
      pk[1][0] = fmaf(t0, w5c.y, pk[1][0]); pk[1][1] = fmaf(t1, w5c.y, pk[1][1]);
      pk[1][2] = fmaf(t2, w5c.y, pk[1][2]); pk[1][3] = fmaf(t3, w5c.y, pk[1][3]);
      pk[2][0] = fmaf(t0, w5c.z, pk[2][0]); pk[2][1] = fmaf(t1, w5c.z, pk[2][1]);
      pk[2][2] = fmaf(t2, w5c.z, pk[2][2]); pk[2][3] = fmaf(t3, w5c.z, pk[2][3]);
      pk[3][0] = fmaf(t0, w5c.w, pk[3][0]); pk[3][1] = fmaf(t1, w5c.w, pk[3][1]);
      pk[3][2] = fmaf(t2, w5c.w, pk[3][2]); pk[3][3] = fmaf(t3, w5c.w, pk[3][3]);
    }
#pragma unroll
    for (int k = 0; k < 4; k++)
#pragma unroll
      for (int r = 0; r < 4; r++) pk[k][r] = gr16(pk[k][r]);
    if (r15 == 0){
#pragma unroll
      for (int r = 0; r < 4; r++){
        int orow = wave * 16 + g * 4 + r;
        if (orow < SQL){
          sak[orow][0] = pk[0][r]; sak[orow][1] = pk[1][r];
          sak[orow][2] = pk[2][r]; sak[orow][3] = pk[3][r];
        }
      }
    }
  }
  __syncthreads();

  // phase 7: a_k = softmax_over_s * mask ; p = p_kt * a_k (into sak)
  {
    int k = wave;
    float v = (lane < SQL) ? sak[lane][k] : -1e30f;
    float m = wmax(v);
    float e = (lane < SQL) ? expf(v - m) : 0.0f;
    float sum = wsum(e);
    if (lane < SQL) sak[lane][k] = (e / sum) * smask[lane] * spkt[lane][k];
  }
  __syncthreads();

  // phase 8: interesting[k] = ln3( sum_s p[s][k] * emb[s] )
  for (int c = t; c < KTOP * H; c += 256){
    int k = c >> 7, h = c & 127;
    float acc = 0.f;
    for (int s = 0; s < SQL; s++) acc = fmaf(sak[s][k], sE[s][h], acc);
    sintr[k][h] = acc;
  }
  __syncthreads();
  {
    int k = wave;
    float v0 = sintr[k][lane], v1 = sintr[k][64 + lane];
    float mu = wsum(v0 + v1) * (1.0f / H);
    float d0 = v0 - mu, d1 = v1 - mu;
    float var = wsum(d0 * d0 + d1 * d1) * (1.0f / H);
    float rs = rsqrtf(var + 1e-5f);
    sintr[k][lane]      = d0 * rs * ln3g[lane]      + ln3b[lane];
    sintr[k][64 + lane] = d1 * rs * ln3g[64 + lane] + ln3b[64 + lane];
  }
  __syncthreads();

  // phase 9: xu = p_kt @ chosen_proto -> sA ; (fused) c_score = tanh(xu@w6)@w7
  for (int c = t; c < SQL * H; c += 256){
    int s = c >> 7, h = c & 127;
    float acc = spkt[s][0] * scp[0][h] + spkt[s][1] * scp[1][h]
              + spkt[s][2] * scp[2][h] + spkt[s][3] * scp[3][h];
    sA[s][h] = acc;
  }
  __syncthreads();
  {
    f32x4 acc[8];
    mm_acc(sA, w6t_hi, w6t_lo, lane, wave, acc);
    float p0 = 0.f, p1 = 0.f, p2 = 0.f, p3 = 0.f;
#pragma unroll
    for (int j = 0; j < 8; j++){
      float w7c = w7[j * 16 + r15];
      p0 = fmaf(tanhf(acc[j][0]), w7c, p0);
      p1 = fmaf(tanhf(acc[j][1]), w7c, p1);
      p2 = fmaf(tanhf(acc[j][2]), w7c, p2);
      p3 = fmaf(tanhf(acc[j][3]), w7c, p3);
    }
    p0 = gr16(p0); p1 = gr16(p1); p2 = gr16(p2); p3 = gr16(p3);
    if (r15 == 0){
      float pv[4] = {p0, p1, p2, p3};
#pragma unroll
      for (int r = 0; r < 4; r++){
        int orow = wave * 16 + g * 4 + r;
        if (orow < SQL) srow[orow] = pv[r] - (1.0f - smask[orow]) * 10000.0f;
      }
    }
  }
  __syncthreads();

  // phase 10: c_w = softmax(c_score); c_apt = ln4(c_w @ xu)
  if (wave == 0){
    float v = (lane < SQL) ? srow[lane] : -1e30f;
    float m = wmax(v);
    float e = (lane < SQL) ? expf(v - m) : 0.0f;
    float sum = wsum(e);
    if (lane < SQL) srow[lane] = e / sum;
  }
  __syncthreads();
  if (t < H){
    float acc = 0.f;
    for (int s = 0; s < SQL; s++) acc = fmaf(srow[s], sA[s][t], acc);
    scapt[t] = acc;
  }
  __syncthreads();
  if (wave == 0){
    float v0 = scapt[lane], v1 = scapt[64 + lane];
    float mu = wsum(v0 + v1) * (1.0f / H);
    float d0 = v0 - mu, d1 = v1 - mu;
    float var = wsum(d0 * d0 + d1 * d1) * (1.0f / H);
    float rs = rsqrtf(var + 1e-5f);
    scapt[lane]      = d0 * rs * ln4g[lane]      + ln4b[lane];
    scapt[64 + lane] = d1 * rs * ln4g[64 + lane] + ln4b[64 + lane];
  }
  __syncthreads();

  // phase 11: e = softmax(e_score/0.1); final = e @ interesting (bf16)
  {
    int k = wave;
    float part = scapt[lane] * sintr[k][lane] + scapt[64 + lane] * sintr[k][64 + lane];
    float sc = wsum(part);
    if (lane == 0) sesc[k] = sc;
  }
  __syncthreads();
  if (t < H){
    float e0 = sesc[0] * 10.0f, e1 = sesc[1] * 10.0f, e2 = sesc[2] * 10.0f, e3 = sesc[3] * 10.0f;
    float m = fmaxf(fmaxf(e0, e1), fmaxf(e2, e3));
    float x0 = expf(e0 - m), x1 = expf(e1 - m), x2 = expf(e2 - m), x3 = expf(e3 - m);
    float inv = 1.0f / (x0 + x1 + x2 + x3);
    float f = (x0 * sintr[0][t] + x1 * sintr[1][t] + x2 * sintr[2][t] + x3 * sintr[3][t]) * inv;
    finalbf[b * H + t] = f2bf(f);
  }
}

// ---------------- weight prep ----------------
extern "C" __global__ void wprep(const float* __restrict__ w1, const float* __restrict__ w3,
                                 const float* __restrict__ w4, const float* __restrict__ w6,
                                 unsigned short* __restrict__ out){
  const float* srcs[4] = {w1, w3, w4, w6};
  const float* src = srcs[blockIdx.x];
  unsigned short* hi = out + blockIdx.x * 32768;
  unsigned short* lo = hi + 16384;
  for (int i = threadIdx.x; i < 16384; i += 256){
    int c = i >> 7, k = i & 127;
    float f = src[k * H + c];
    unsigned short h = f2bf(f);
    hi[i] = h;
    lo[i] = f2bf(f - bf2f(h));
  }
}

// ---------------- item_emb f32 -> bf16 ----------------
extern "C" __global__ void conv_bf16(const float* __restrict__ in,
                                     unsigned short* __restrict__ out, int n4){
  int i = blockIdx.x * blockDim.x + threadIdx.x;
  int stride = gridDim.x * blockDim.x;
  for (; i < n4; i += stride){
    float4 v = reinterpret_cast<const float4*>(in)[i];
    union { unsigned short u[4]; uint2 v2; } o;
    o.u[0] = f2bf(v.x); o.u[1] = f2bf(v.y); o.u[2] = f2bf(v.z); o.u[3] = f2bf(v.w);
    reinterpret_cast<uint2*>(out)[i] = o.v2;
  }
}

// ---------------- scores = final @ item^T (bf16 MFMA via LDS, 128x128 tiles) ----------------
#define GBM 128
#define GBN 128
#define LDT 136

extern "C" __global__ __launch_bounds__(256)
void gemm_scores(const unsigned short* __restrict__ A,   // final [1024][128]
                 const unsigned short* __restrict__ Bm,  // items [100000][128]
                 float* __restrict__ C)
{
  __shared__ __align__(16) unsigned short sA[GBM][LDT];
  __shared__ __align__(16) unsigned short sB[GBN][LDT];
  const int t = threadIdx.x, lane = t & 63, wave = t >> 6;
  const int r15 = lane & 15, g = lane >> 4;
  const int n0 = blockIdx.x * GBN;
  const int m0 = blockIdx.y * GBM;

  for (int c = t; c < GBM * 16; c += 256){
    int r = c >> 4, q = c & 15;
    uint4 v = reinterpret_cast<const uint4*>(A + (m0 + r) * H)[q];
    *reinterpret_cast<uint4*>(&sA[r][q * 8]) = v;
  }
  for (int c = t; c < GBN * 16; c += 256){
    int r = c >> 4, q = c & 15;
    int n = n0 + r;
    uint4 v = make_uint4(0u, 0u, 0u, 0u);
    if (n < ITEMS) v = reinterpret_cast<const uint4*>(Bm + (size_t)n * H)[q];
    *reinterpret_cast<uint4*>(&sB[r][q * 8]) = v;
  }
  __syncthreads();

  const int wm = wave >> 1, wn = wave & 1;   // 2x2 wave grid, 64x64 per wave
  f32x4 acc[4][4];
#pragma unroll
  for (int i = 0; i < 4; i++)
#pragma unroll
    for (int j = 0; j < 4; j++) acc[i][j] = (f32x4){0.f, 0.f, 0.f, 0.f};

#pragma unroll
  for (int ks = 0; ks < 4; ks++){
    bf16x8 af[4], bfr[4];
#pragma unroll
    for (int i = 0; i < 4; i++)
      af[i] = *reinterpret_cast<const bf16x8*>(&sA[wm * 64 + i * 16 + r15][ks * 32 + g * 8]);
#pragma unroll
    for (int j = 0; j < 4; j++)
      bfr[j] = *reinterpret_cast<const bf16x8*>(&sB[wn * 64 + j * 16 + r15][ks * 32 + g * 8]);
#pragma unroll
    for (int i = 0; i < 4; i++)
#pragma unroll
      for (int j = 0; j < 4; j++)
        acc[i][j] = __builtin_amdgcn_mfma_f32_16x16x32_bf16(af[i], bfr[j], acc[i][j], 0, 0, 0);
  }

#pragma unroll
  for (int i = 0; i < 4; i++){
    int mrow = m0 + wm * 64 + i * 16 + g * 4;
#pragma unroll
    for (int j = 0; j < 4; j++){
      int ncol = n0 + wn * 64 + j * 16 + r15;
      if (ncol < ITEMS){
#pragma unroll
        for (int r = 0; r < 4; r++)
          C[(size_t)(mrow + r) * ITEMS + ncol] = acc[i][j][r];
      }
    }
  }
}

// ---------------- prototype covariance regularizer ----------------
extern "C" __global__ void proto_mean(const float* __restrict__ proto,
                                      float* __restrict__ mean, float* __restrict__ accum){
  int h = threadIdx.x;
  if (h < 2) accum[h] = 0.0f;
  float acc = 0.f;
  for (int l = 0; l < LPROTO; l++) acc += proto[l * H + h];
  mean[h] = acc * (1.0f / LPROTO);
}

extern "C" __global__ __launch_bounds__(256)
void proto_cov(const float* __restrict__ proto, const float* __restrict__ mean,
               float* __restrict__ accum){
  __shared__ float ci[H];
  __shared__ float red[256];
  int i = blockIdx.x, t = threadIdx.x;
  if (t < H) ci[t] = proto[i * H + t] - mean[t];
  __syncthreads();
  float total = 0.f;
  for (int j = t; j < LPROTO; j += 256){
    float acc = 0.f;
    for (int h = 0; h < H; h++) acc = fmaf(ci[h], proto[j * H + h] - mean[h], acc);
    float m = acc * (1.0f / H);
    total += m * m;
    if (j == i) atomicAdd(&accum[1], m * m);
  }
  red[t] = total; __syncthreads();
  for (int o = 128; o; o >>= 1){ if (t < o) red[t] += red[t + o]; __syncthreads(); }
  if (t == 0) atomicAdd(&accum[0], red[0]);
}

extern "C" __global__ void lc_final(const float* __restrict__ accum, float* __restrict__ out){
  out[(size_t)BQ * ITEMS] = 0.1f * 0.5f * (sqrtf(accum[0]) - sqrtf(accum[1]));
}

// ---------------- launch ----------------
extern "C" void kernel_launch(void* const* d_in, const int* in_sizes, int n_in,
                              void* d_out, int out_size, void* d_ws, size_t ws_size,
                              hipStream_t stream){
  const float* item  = (const float*)d_in[0];
  const float* pos   = (const float*)d_in[1];
  const float* proto = (const float*)d_in[2];
  const float* w1 = (const float*)d_in[3];
  const float* w2 = (const float*)d_in[4];
  const float* w3 = (const float*)d_in[5];
  const float* w4 = (const float*)d_in[6];
  const float* w5 = (const float*)d_in[7];
  const float* w6 = (const float*)d_in[8];
  const float* w7 = (const float*)d_in[9];
  const float* ln1g = (const float*)d_in[10];
  const float* ln1b = (const float*)d_in[11];
  const float* ln2g = (const float*)d_in[12];
  const float* ln2b = (const float*)d_in[13];
  const float* ln3g = (const float*)d_in[14];
  const float* ln3b = (const float*)d_in[15];
  const float* ln4g = (const float*)d_in[16];
  const float* ln4b = (const float*)d_in[17];
  const int* seq = (const int*)d_in[18];
  float* out = (float*)d_out;

  char* ws = (char*)d_ws;
  float* accum = (float*)ws;
  float* mean  = (float*)(ws + 256);
  unsigned short* finalbf = (unsigned short*)(ws + 1024);
  unsigned short* itembf  = (unsigned short*)(ws + 263168);
  unsigned short* wtbuf   = (unsigned short*)(ws + 25863168);

  wprep<<<4, 256, 0, stream>>>(w1, w3, w4, w6, wtbuf);
  conv_bf16<<<2048, 256, 0, stream>>>(item, itembf, ITEMS * H / 4);

  sine_row<<<BQ, 256, 0, stream>>>(item, pos, proto, w2, w5, w7, wtbuf,
                                   ln1g, ln1b, ln2g, ln2b, ln3g, ln3b, ln4g, ln4b,
                                   seq, finalbf);

  gemm_scores<<<dim3((ITEMS + GBN - 1) / GBN, BQ / GBM), 256, 0, stream>>>(finalbf, itembf, out);

  proto_mean<<<1, 128, 0, stream>>>(proto, mean, accum);
  proto_cov<<<LPROTO, 256, 0, stream>>>(proto, mean, accum);
  lc_final<<<1, 1, 0, stream>>>(accum, out);
}

// Round 6
// 365.985 us; speedup vs baseline: 1.6141x; 1.0353x over previous
//
#include <hip/hip_runtime.h>
#include <hip/hip_bf16.h>

#define H 128
#define H2 132   // padded f32 LDS row stride
#define SQL 50
#define LPROTO 500
#define KTOP 4
#define BQ 1024
#define ITEMS 100000

typedef __attribute__((ext_vector_type(8))) short bf16x8;
typedef __attribute__((ext_vector_type(4))) float f32x4;

__device__ __forceinline__ float wsum(float v){
#pragma unroll
  for (int o = 32; o; o >>= 1) v += __shfl_xor(v, o, 64);
  return v;
}
__device__ __forceinline__ float wmax(float v){
#pragma unroll
  for (int o = 32; o; o >>= 1) v = fmaxf(v, __shfl_xor(v, o, 64));
  return v;
}
// 16-lane-group sum
__device__ __forceinline__ float gr16(float v){
  v += __shfl_xor(v, 1, 64);
  v += __shfl_xor(v, 2, 64);
  v += __shfl_xor(v, 4, 64);
  v += __shfl_xor(v, 8, 64);
  return v;
}
__device__ __forceinline__ unsigned short f2bf(float x){
  unsigned int u = __builtin_bit_cast(unsigned int, x);
  unsigned int r = u + 0x7fffu + ((u >> 16) & 1u);
  return (unsigned short)(r >> 16);
}
__device__ __forceinline__ float bf2f(unsigned short h){
  unsigned int u = ((unsigned int)h) << 16;
  return __builtin_bit_cast(float, u);
}

// Shared body: builds hi/lo A-fragments from xs[8] and runs the 8-col-tile MFMA sweep.
__device__ __forceinline__ void mm_core(const float xs[4][8],
                                        const unsigned short* __restrict__ wt_hi,
                                        const unsigned short* __restrict__ wt_lo,
                                        int r15, int kof, f32x4* acc)
{
  bf16x8 ah[4], al[4];
#pragma unroll
  for (int ks = 0; ks < 4; ks++){
    bf16x8 h, l;
#pragma unroll
    for (int e = 0; e < 8; e++){
      unsigned short hb = f2bf(xs[ks][e]);
      float rem = xs[ks][e] - bf2f(hb);
      h[e] = (short)hb;
      l[e] = (short)f2bf(rem);
    }
    ah[ks] = h; al[ks] = l;
  }
#pragma unroll
  for (int j = 0; j < 8; j++){
    const unsigned short* bp = wt_hi + (j * 16 + r15) * H + kof;
    const unsigned short* lp = wt_lo + (j * 16 + r15) * H + kof;
    f32x4 a = (f32x4){0.f, 0.f, 0.f, 0.f};
#pragma unroll
    for (int ks = 0; ks < 4; ks++){
      bf16x8 bh = *reinterpret_cast<const bf16x8*>(bp + ks * 32);
      bf16x8 bl = *reinterpret_cast<const bf16x8*>(lp + ks * 32);
      a = __builtin_amdgcn_mfma_f32_16x16x32_bf16(ah[ks], bh, a, 0, 0, 0);
      a = __builtin_amdgcn_mfma_f32_16x16x32_bf16(al[ks], bh, a, 0, 0, 0);
      a = __builtin_amdgcn_mfma_f32_16x16x32_bf16(ah[ks], bl, a, 0, 0, 0);
    }
    acc[j] = a;
  }
}

// acc[j][r] = (src @ W)[wave*16 + g*4 + r][j*16 + r15]
__device__ __forceinline__ void mm_acc(const float (*src)[H2],
                                       const unsigned short* __restrict__ wt_hi,
                                       const unsigned short* __restrict__ wt_lo,
                                       int lane, int wave, f32x4* acc)
{
  const int r15 = lane & 15, g = lane >> 4, kof = g * 8;
  const int row = wave * 16 + r15;
  const int srw = (row < SQL) ? row : 0;
  float xs[4][8];
#pragma unroll
  for (int ks = 0; ks < 4; ks++){
    const float* p = &src[srw][ks * 32 + kof];
    float4 x0 = *reinterpret_cast<const float4*>(p);
    float4 x1 = *reinterpret_cast<const float4*>(p + 4);
    xs[ks][0]=x0.x; xs[ks][1]=x0.y; xs[ks][2]=x0.z; xs[ks][3]=x0.w;
    xs[ks][4]=x1.x; xs[ks][5]=x1.y; xs[ks][6]=x1.z; xs[ks][7]=x1.w;
  }
  mm_core(xs, wt_hi, wt_lo, r15, kof, acc);
}

// same, but A-row = src[row] + pos_emb[SQL-row]  (emb recomputed on the fly)
__device__ __forceinline__ void mm_acc_pos(const float (*src)[H2],
                                           const float* __restrict__ pos_emb,
                                           const unsigned short* __restrict__ wt_hi,
                                           const unsigned short* __restrict__ wt_lo,
                                           int lane, int wave, f32x4* acc)
{
  const int r15 = lane & 15, g = lane >> 4, kof = g * 8;
  const int row = wave * 16 + r15;
  const int srw = (row < SQL) ? row : 0;
  const float* pp = pos_emb + (SQL - srw) * H;
  float xs[4][8];
#pragma unroll
  for (int ks = 0; ks < 4; ks++){
    const float* p = &src[srw][ks * 32 + kof];
    float4 x0 = *reinterpret_cast<const float4*>(p);
    float4 x1 = *reinterpret_cast<const float4*>(p + 4);
    float4 p0 = *reinterpret_cast<const float4*>(pp + ks * 32 + kof);
    float4 p1 = *reinterpret_cast<const float4*>(pp + ks * 32 + kof + 4);
    xs[ks][0]=x0.x+p0.x; xs[ks][1]=x0.y+p0.y; xs[ks][2]=x0.z+p0.z; xs[ks][3]=x0.w+p0.w;
    xs[ks][4]=x1.x+p1.x; xs[ks][5]=x1.y+p1.y; xs[ks][6]=x1.z+p1.z; xs[ks][7]=x1.w+p1.w;
  }
  mm_core(xs, wt_hi, wt_lo, r15, kof, acc);
}

// ---------------- per-batch-row pipeline: one block (4 waves) per b ----------------
extern "C" __global__ __launch_bounds__(256, 4)
void sine_row(const float* __restrict__ item_emb, const float* __restrict__ pos_emb,
              const float* __restrict__ proto,
              const float* __restrict__ w2, const float* __restrict__ w5,
              const float* __restrict__ w7,
              const unsigned short* __restrict__ wt,
              const float* __restrict__ ln1g, const float* __restrict__ ln1b,
              const float* __restrict__ ln2g, const float* __restrict__ ln2b,
              const float* __restrict__ ln3g, const float* __restrict__ ln3b,
              const float* __restrict__ ln4g, const float* __restrict__ ln4b,
              const int* __restrict__ seq,
              unsigned short* __restrict__ finalbf)
{
  __shared__ __align__(16) float sA[SQL][H2];     // ie -> xu
  __shared__ __align__(16) float scp[KTOP][H];
  __shared__ __align__(16) float slncp[KTOP][H];
  __shared__ __align__(16) float sintr[KTOP][H];
  __shared__ __align__(16) float svcv[H];
  __shared__ __align__(16) float scapt[H];
  __shared__ float srow[SQL];
  __shared__ float smask[SQL];
  __shared__ float spkt[SQL][KTOP];
  __shared__ float sak[SQL][KTOP];
  __shared__ float ssc[LPROTO];
  __shared__ float schs[KTOP];
  __shared__ int   srank[KTOP];
  __shared__ float sesc[KTOP];

  const int b = blockIdx.x;
  const int t = threadIdx.x;
  const int lane = t & 63;
  const int wave = t >> 6;
  const int r15 = lane & 15;
  const int g   = lane >> 4;
  const int* sq = seq + b * SQL;

  const unsigned short* w1t_hi = wt;
  const unsigned short* w1t_lo = wt + 16384;
  const unsigned short* w3t_hi = wt + 32768;
  const unsigned short* w3t_lo = wt + 49152;
  const unsigned short* w4t_hi = wt + 65536;
  const unsigned short* w4t_lo = wt + 81920;
  const unsigned short* w6t_hi = wt + 98304;
  const unsigned short* w6t_lo = wt + 114688;

  // phase 0: mask + gather ie
  if (t < SQL) smask[t] = (sq[t] != 0) ? 1.0f : 0.0f;
  for (int c = t; c < SQL * (H / 4); c += 256){
    int s = c >> 5, q = c & 31;
    int idx = sq[s];
    float4 v = reinterpret_cast<const float4*>(item_emb)[idx * (H / 4) + q];
    reinterpret_cast<float4*>(&sA[s][0])[q] = v;
  }
  __syncthreads();

  // phase 1 (fused): sa_score = tanh(ie@w1)@w2 - (1-mask)*1e4
  {
    f32x4 acc[8];
    mm_acc(sA, w1t_hi, w1t_lo, lane, wave, acc);
    float p0 = 0.f, p1 = 0.f, p2 = 0.f, p3 = 0.f;
#pragma unroll
    for (int j = 0; j < 8; j++){
      float w2c = w2[j * 16 + r15];
      p0 = fmaf(tanhf(acc[j][0]), w2c, p0);
      p1 = fmaf(tanhf(acc[j][1]), w2c, p1);
      p2 = fmaf(tanhf(acc[j][2]), w2c, p2);
      p3 = fmaf(tanhf(acc[j][3]), w2c, p3);
    }
    p0 = gr16(p0); p1 = gr16(p1); p2 = gr16(p2); p3 = gr16(p3);
    if (r15 == 0){
      float pv[4] = {p0, p1, p2, p3};
#pragma unroll
      for (int r = 0; r < 4; r++){
        int orow = wave * 16 + g * 4 + r;
        if (orow < SQL) srow[orow] = pv[r] - (1.0f - smask[orow]) * 10000.0f;
      }
    }
  }
  __syncthreads();

  // phase 2: alpha = softmax(sa_score); vcv = alpha @ ie
  if (wave == 0){
    float v = (lane < SQL) ? srow[lane] : -1e30f;
    float m = wmax(v);
    float e = (lane < SQL) ? expf(v - m) : 0.0f;
    float sum = wsum(e);
    if (lane < SQL) srow[lane] = e / sum;
  }
  __syncthreads();
  if (t < H){
    float acc = 0.f;
    for (int s = 0; s < SQL; s++) acc = fmaf(srow[s], sA[s][t], acc);
    svcv[t] = acc;
  }
  __syncthreads();

  // phase 3: proto scores + stable top-4 + chosen/ln2 protos
  for (int l = t; l < LPROTO; l += 256){
    const float4* pr = reinterpret_cast<const float4*>(proto + l * H);
    const float4* vc = reinterpret_cast<const float4*>(svcv);
    float acc = 0.f;
    for (int q = 0; q < H / 4; q++){
      float4 p = pr[q], v = vc[q];
      acc += p.x * v.x + p.y * v.y + p.z * v.z + p.w * v.w;
    }
    ssc[l] = acc;
  }
  __syncthreads();
  if (wave == 0){
    float cand[8];
#pragma unroll
    for (int i = 0; i < 8; i++){
      int l = lane + 64 * i;
      cand[i] = (l < LPROTO) ? ssc[l] : -1e30f;
    }
    for (int k = 0; k < KTOP; k++){
      float bv = -1e30f; int bi = 0x7fffffff;
#pragma unroll
      for (int i = 0; i < 8; i++){
        int l = lane + 64 * i;
        if (cand[i] > bv || (cand[i] == bv && l < bi)){ bv = cand[i]; bi = l; }
      }
#pragma unroll
      for (int o = 32; o; o >>= 1){
        float ov = __shfl_xor(bv, o, 64);
        int   oi = __shfl_xor(bi, o, 64);
        if (ov > bv || (ov == bv && oi < bi)){ bv = ov; bi = oi; }
      }
      if (lane == 0){ schs[k] = bv; srank[k] = bi; }
      int li = bi - lane;
#pragma unroll
      for (int i = 0; i < 8; i++) if (64 * i == li) cand[i] = -1e30f;
    }
  }
  __syncthreads();
  {
    int k = wave;
    int r = srank[k];
    float sg = 1.0f / (1.0f + expf(-schs[k]));
    float v0 = sg * proto[r * H + lane];
    float v1 = sg * proto[r * H + 64 + lane];
    float mu = wsum(v0 + v1) * (1.0f / H);
    float d0 = v0 - mu, d1 = v1 - mu;
    float var = wsum(d0 * d0 + d1 * d1) * (1.0f / H);
    float rs = rsqrtf(var + 1e-5f);
    scp[k][lane] = v0; scp[k][64 + lane] = v1;
    slncp[k][lane]      = d0 * rs * ln2g[lane]      + ln2b[lane];
    slncp[k][64 + lane] = d1 * rs * ln2g[64 + lane] + ln2b[64 + lane];
  }
  __syncthreads();

  // phase 5 (fused): p_kt = softmax_k( ln1(ie@w3) . ln2cp ) * mask
  {
    f32x4 acc[8];
    mm_acc(sA, w3t_hi, w3t_lo, lane, wave, acc);
    float s0 = 0.f, s1 = 0.f, s2 = 0.f, s3 = 0.f;
#pragma unroll
    for (int j = 0; j < 8; j++){ s0 += acc[j][0]; s1 += acc[j][1]; s2 += acc[j][2]; s3 += acc[j][3]; }
    float mu0 = gr16(s0) * (1.0f / H), mu1 = gr16(s1) * (1.0f / H);
    float mu2 = gr16(s2) * (1.0f / H), mu3 = gr16(s3) * (1.0f / H);
    float q0 = 0.f, q1 = 0.f, q2 = 0.f, q3 = 0.f;
#pragma unroll
    for (int j = 0; j < 8; j++){
      float d0 = acc[j][0] - mu0, d1 = acc[j][1] - mu1;
      float d2 = acc[j][2] - mu2, d3 = acc[j][3] - mu3;
      q0 = fmaf(d0, d0, q0); q1 = fmaf(d1, d1, q1);
      q2 = fmaf(d2, d2, q2); q3 = fmaf(d3, d3, q3);
    }
    float rs0 = rsqrtf(gr16(q0) * (1.0f / H) + 1e-5f);
    float rs1 = rsqrtf(gr16(q1) * (1.0f / H) + 1e-5f);
    float rs2 = rsqrtf(gr16(q2) * (1.0f / H) + 1e-5f);
    float rs3 = rsqrtf(gr16(q3) * (1.0f / H) + 1e-5f);
    float pk[4][4];
#pragma unroll
    for (int k = 0; k < 4; k++)
#pragma unroll
      for (int r = 0; r < 4; r++) pk[k][r] = 0.f;
#pragma unroll
    for (int j = 0; j < 8; j++){
      int c = j * 16 + r15;
      float gg = ln1g[c], bb = ln1b[c];
      float l0 = fmaf((acc[j][0] - mu0) * rs0, gg, bb);
      float l1 = fmaf((acc[j][1] - mu1) * rs1, gg, bb);
      float l2 = fmaf((acc[j][2] - mu2) * rs2, gg, bb);
      float l3 = fmaf((acc[j][3] - mu3) * rs3, gg, bb);
#pragma unroll
      for (int k = 0; k < 4; k++){
        float w = slncp[k][c];
        pk[k][0] = fmaf(l0, w, pk[k][0]);
        pk[k][1] = fmaf(l1, w, pk[k][1]);
        pk[k][2] = fmaf(l2, w, pk[k][2]);
        pk[k][3] = fmaf(l3, w, pk[k][3]);
      }
    }
#pragma unroll
    for (int k = 0; k < 4; k++)
#pragma unroll
      for (int r = 0; r < 4; r++) pk[k][r] = gr16(pk[k][r]);
    if (r15 == 0){
#pragma unroll
      for (int r = 0; r < 4; r++){
        int orow = wave * 16 + g * 4 + r;
        if (orow < SQL){
          float m = fmaxf(fmaxf(pk[0][r], pk[1][r]), fmaxf(pk[2][r], pk[3][r]));
          float e0 = expf(pk[0][r] - m), e1 = expf(pk[1][r] - m);
          float e2 = expf(pk[2][r] - m), e3 = expf(pk[3][r] - m);
          float inv = 1.0f / (e0 + e1 + e2 + e3);
          float msk = smask[orow];
          spkt[orow][0] = e0 * inv * msk; spkt[orow][1] = e1 * inv * msk;
          spkt[orow][2] = e2 * inv * msk; spkt[orow][3] = e3 * inv * msk;
        }
      }
    }
  }
  __syncthreads();

  // phase 6 (fused, emb on the fly): a_k_score[s][k] = tanh((ie+pos)@w4)@w5
  {
    f32x4 acc[8];
    mm_acc_pos(sA, pos_emb, w4t_hi, w4t_lo, lane, wave, acc);
    float pk[4][4];
#pragma unroll
    for (int k = 0; k < 4; k++)
#pragma unroll
      for (int r = 0; r < 4; r++) pk[k][r] = 0.f;
#pragma unroll
    for (int j = 0; j < 8; j++){
      int c = j * 16 + r15;
      float4 w5c = *reinterpret_cast<const float4*>(w5 + c * 4);
      float t0 = tanhf(acc[j][0]), t1 = tanhf(acc[j][1]);
      float t2 = tanhf(acc[j][2]), t3 = tanhf(acc[j][3]);
      pk[0][0] = fmaf(t0, w5c.x, pk[0][0]); pk[0][1] = fmaf(t1, w5c.x, pk[0][1]);
      pk[0][2] = fmaf(t2, w5c.x, pk[0][2]); pk[0][3] = fmaf(t3, w5c.x, pk[0][3]);
      pk[1][0] = fmaf(t0, w5c.y, pk[1][0]); pk[1][1] = fmaf(t1, w5c.y, pk[1][1]);
      pk[1][2] = fmaf(t2, w5c.y, pk[1][2]); pk[1][3] = fmaf(t3, w5c.y, pk[1][3]);
      pk[2][0] = fmaf(t0, w5c.z, pk[2][0]); pk[2][1] = fmaf(t1, w5c.z, pk[2][1]);
      pk[2][2] = fmaf(t2, w5c.z, pk[2][2]); pk[2][3] = fmaf(t3, w5c.z, pk[2][3]);
      pk[3][0] = fmaf(t0, w5c.w, pk[3][0]); pk[3][1] = fmaf(t1, w5c.w, pk[3][1]);
      pk[3][2] = fmaf(t2, w5c.w, pk[3][2]); pk[3][3] = fmaf(t3, w5c.w, pk[3][3]);
    }
#pragma unroll
    for (int k = 0; k < 4; k++)
#pragma unroll
      for (int r = 0; r < 4; r++) pk[k][r] = gr16(pk[k][r]);
    if (r15 == 0){
#pragma unroll
      for (int r = 0; r < 4; r++){
        int orow = wave * 16 + g * 4 + r;
        if (orow < SQL){
          sak[orow][0] = pk[0][r]; sak[orow][1] = pk[1][r];
          sak[orow][2] = pk[2][r]; sak[orow][3] = pk[3][r];
        }
      }
    }
  }
  __syncthreads();

  // phase 7: a_k = softmax_over_s * mask ; p = p_kt * a_k (into sak)
  {
    int k = wave;
    float v = (lane < SQL) ? sak[lane][k] : -1e30f;
    float m = wmax(v);
    float e = (lane < SQL) ? expf(v - m) : 0.0f;
    float sum = wsum(e);
    if (lane < SQL) sak[lane][k] = (e / sum) * smask[lane] * spkt[lane][k];
  }
  __syncthreads();

  // phase 8: interesting[k] = ln3( sum_s p[s][k] * (ie+pos)[s] )
  for (int c = t; c < KTOP * H; c += 256){
    int k = c >> 7, h = c & 127;
    float acc = 0.f;
    for (int s = 0; s < SQL; s++)
      acc = fmaf(sak[s][k], sA[s][h] + pos_emb[(SQL - s) * H + h], acc);
    sintr[k][h] = acc;
  }
  __syncthreads();
  {
    int k = wave;
    float v0 = sintr[k][lane], v1 = sintr[k][64 + lane];
    float mu = wsum(v0 + v1) * (1.0f / H);
    float d0 = v0 - mu, d1 = v1 - mu;
    float var = wsum(d0 * d0 + d1 * d1) * (1.0f / H);
    float rs = rsqrtf(var + 1e-5f);
    sintr[k][lane]      = d0 * rs * ln3g[lane]      + ln3b[lane];
    sintr[k][64 + lane] = d1 * rs * ln3g[64 + lane] + ln3b[64 + lane];
  }
  __syncthreads();

  // phase 9: xu = p_kt @ chosen_proto -> sA ; (fused) c_score = tanh(xu@w6)@w7
  for (int c = t; c < SQL * H; c += 256){
    int s = c >> 7, h = c & 127;
    float acc = spkt[s][0] * scp[0][h] + spkt[s][1] * scp[1][h]
              + spkt[s][2] * scp[2][h] + spkt[s][3] * scp[3][h];
    sA[s][h] = acc;
  }
  __syncthreads();
  {
    f32x4 acc[8];
    mm_acc(sA, w6t_hi, w6t_lo, lane, wave, acc);
    float p0 = 0.f, p1 = 0.f, p2 = 0.f, p3 = 0.f;
#pragma unroll
    for (int j = 0; j < 8; j++){
      float w7c = w7[j * 16 + r15];
      p0 = fmaf(tanhf(acc[j][0]), w7c, p0);
      p1 = fmaf(tanhf(acc[j][1]), w7c, p1);
      p2 = fmaf(tanhf(acc[j][2]), w7c, p2);
      p3 = fmaf(tanhf(acc[j][3]), w7c, p3);
    }
    p0 = gr16(p0); p1 = gr16(p1); p2 = gr16(p2); p3 = gr16(p3);
    if (r15 == 0){
      float pv[4] = {p0, p1, p2, p3};
#pragma unroll
      for (int r = 0; r < 4; r++){
        int orow = wave * 16 + g * 4 + r;
        if (orow < SQL) srow[orow] = pv[r] - (1.0f - smask[orow]) * 10000.0f;
      }
    }
  }
  __syncthreads();

  // phase 10: c_w = softmax(c_score); c_apt = ln4(c_w @ xu)
  if (wave == 0){
    float v = (lane < SQL) ? srow[lane] : -1e30f;
    float m = wmax(v);
    float e = (lane < SQL) ? expf(v - m) : 0.0f;
    float sum = wsum(e);
    if (lane < SQL) srow[lane] = e / sum;
  }
  __syncthreads();
  if (t < H){
    float acc = 0.f;
    for (int s = 0; s < SQL; s++) acc = fmaf(srow[s], sA[s][t], acc);
    scapt[t] = acc;
  }
  __syncthreads();
  if (wave == 0){
    float v0 = scapt[lane], v1 = scapt[64 + lane];
    float mu = wsum(v0 + v1) * (1.0f / H);
    float d0 = v0 - mu, d1 = v1 - mu;
    float var = wsum(d0 * d0 + d1 * d1) * (1.0f / H);
    float rs = rsqrtf(var + 1e-5f);
    scapt[lane]      = d0 * rs * ln4g[lane]      + ln4b[lane];
    scapt[64 + lane] = d1 * rs * ln4g[64 + lane] + ln4b[64 + lane];
  }
  __syncthreads();

  // phase 11: e = softmax(e_score/0.1); final = e @ interesting (bf16)
  {
    int k = wave;
    float part = scapt[lane] * sintr[k][lane] + scapt[64 + lane] * sintr[k][64 + lane];
    float sc = wsum(part);
    if (lane == 0) sesc[k] = sc;
  }
  __syncthreads();
  if (t < H){
    float e0 = sesc[0] * 10.0f, e1 = sesc[1] * 10.0f, e2 = sesc[2] * 10.0f, e3 = sesc[3] * 10.0f;
    float m = fmaxf(fmaxf(e0, e1), fmaxf(e2, e3));
    float x0 = expf(e0 - m), x1 = expf(e1 - m), x2 = expf(e2 - m), x3 = expf(e3 - m);
    float inv = 1.0f / (x0 + x1 + x2 + x3);
    float f = (x0 * sintr[0][t] + x1 * sintr[1][t] + x2 * sintr[2][t] + x3 * sintr[3][t]) * inv;
    finalbf[b * H + t] = f2bf(f);
  }
}

// ---------------- weight prep ----------------
extern "C" __global__ void wprep(const float* __restrict__ w1, const float* __restrict__ w3,
                                 const float* __restrict__ w4, const float* __restrict__ w6,
                                 unsigned short* __restrict__ out){
  const float* srcs[4] = {w1, w3, w4, w6};
  const float* src = srcs[blockIdx.x];
  unsigned short* hi = out + blockIdx.x * 32768;
  unsigned short* lo = hi + 16384;
  for (int i = threadIdx.x; i < 16384; i += 256){
    int c = i >> 7, k = i & 127;
    float f = src[k * H + c];
    unsigned short h = f2bf(f);
    hi[i] = h;
    lo[i] = f2bf(f - bf2f(h));
  }
}

// ---------------- item_emb f32 -> bf16 ----------------
extern "C" __global__ void conv_bf16(const float* __restrict__ in,
                                     unsigned short* __restrict__ out, int n4){
  int i = blockIdx.x * blockDim.x + threadIdx.x;
  int stride = gridDim.x * blockDim.x;
  for (; i < n4; i += stride){
    float4 v = reinterpret_cast<const float4*>(in)[i];
    union { unsigned short u[4]; uint2 v2; } o;
    o.u[0] = f2bf(v.x); o.u[1] = f2bf(v.y); o.u[2] = f2bf(v.z); o.u[3] = f2bf(v.w);
    reinterpret_cast<uint2*>(out)[i] = o.v2;
  }
}

// ---------------- scores = final @ item^T (bf16 MFMA via LDS, 128x128 tiles) ----------------
#define GBM 128
#define GBN 128
#define LDT 136

extern "C" __global__ __launch_bounds__(256)
void gemm_scores(const unsigned short* __restrict__ A,   // final [1024][128]
                 const unsigned short* __restrict__ Bm,  // items [100000][128]
                 float* __restrict__ C)
{
  __shared__ __align__(16) unsigned short sA[GBM][LDT];
  __shared__ __align__(16) unsigned short sB[GBN][LDT];
  const int t = threadIdx.x, lane = t & 63, wave = t >> 6;
  const int r15 = lane & 15, g = lane >> 4;
  const int n0 = blockIdx.x * GBN;
  const int m0 = blockIdx.y * GBM;

  for (int c = t; c < GBM * 16; c += 256){
    int r = c >> 4, q = c & 15;
    uint4 v = reinterpret_cast<const uint4*>(A + (m0 + r) * H)[q];
    *reinterpret_cast<uint4*>(&sA[r][q * 8]) = v;
  }
  for (int c = t; c < GBN * 16; c += 256){
    int r = c >> 4, q = c & 15;
    int n = n0 + r;
    uint4 v = make_uint4(0u, 0u, 0u, 0u);
    if (n < ITEMS) v = reinterpret_cast<const uint4*>(Bm + (size_t)n * H)[q];
    *reinterpret_cast<uint4*>(&sB[r][q * 8]) = v;
  }
  __syncthreads();

  const int wm = wave >> 1, wn = wave & 1;
  f32x4 acc[4][4];
#pragma unroll
  for (int i = 0; i < 4; i++)
#pragma unroll
    for (int j = 0; j < 4; j++) acc[i][j] = (f32x4){0.f, 0.f, 0.f, 0.f};

#pragma unroll
  for (int ks = 0; ks < 4; ks++){
    bf16x8 af[4], bfr[4];
#pragma unroll
    for (int i = 0; i < 4; i++)
      af[i] = *reinterpret_cast<const bf16x8*>(&sA[wm * 64 + i * 16 + r15][ks * 32 + g * 8]);
#pragma unroll
    for (int j = 0; j < 4; j++)
      bfr[j] = *reinterpret_cast<const bf16x8*>(&sB[wn * 64 + j * 16 + r15][ks * 32 + g * 8]);
#pragma unroll
    for (int i = 0; i < 4; i++)
#pragma unroll
      for (int j = 0; j < 4; j++)
        acc[i][j] = __builtin_amdgcn_mfma_f32_16x16x32_bf16(af[i], bfr[j], acc[i][j], 0, 0, 0);
  }

#pragma unroll
  for (int i = 0; i < 4; i++){
    int mrow = m0 + wm * 64 + i * 16 + g * 4;
#pragma unroll
    for (int j = 0; j < 4; j++){
      int ncol = n0 + wn * 64 + j * 16 + r15;
      if (ncol < ITEMS){
#pragma unroll
        for (int r = 0; r < 4; r++)
          C[(size_t)(mrow + r) * ITEMS + ncol] = acc[i][j][r];
      }
    }
  }
}

// ---------------- prototype covariance regularizer ----------------
extern "C" __global__ void proto_mean(const float* __restrict__ proto,
                                      float* __restrict__ mean, float* __restrict__ accum){
  int h = threadIdx.x;
  if (h < 2) accum[h] = 0.0f;
  float acc = 0.f;
  for (int l = 0; l < LPROTO; l++) acc += proto[l * H + h];
  mean[h] = acc * (1.0f / LPROTO);
}

extern "C" __global__ __launch_bounds__(256)
void proto_cov(const float* __restrict__ proto, const float* __restrict__ mean,
               float* __restrict__ accum){
  __shared__ float ci[H];
  __shared__ float red[256];
  int i = blockIdx.x, t = threadIdx.x;
  if (t < H) ci[t] = proto[i * H + t] - mean[t];
  __syncthreads();
  float total = 0.f;
  for (int j = t; j < LPROTO; j += 256){
    float acc = 0.f;
    for (int h = 0; h < H; h++) acc = fmaf(ci[h], proto[j * H + h] - mean[h], acc);
    float m = acc * (1.0f / H);
    total += m * m;
    if (j == i) atomicAdd(&accum[1], m * m);
  }
  red[t] = total; __syncthreads();
  for (int o = 128; o; o >>= 1){ if (t < o) red[t] += red[t + o]; __syncthreads(); }
  if (t == 0) atomicAdd(&accum[0], red[0]);
}

extern "C" __global__ void lc_final(const float* __restrict__ accum, float* __restrict__ out){
  out[(size_t)BQ * ITEMS] = 0.1f * 0.5f * (sqrtf(accum[0]) - sqrtf(accum[1]));
}

// ---------------- launch ----------------
extern "C" void kernel_launch(void* const* d_in, const int* in_sizes, int n_in,
                              void* d_out, int out_size, void* d_ws, size_t ws_size,
                              hipStream_t stream){
  const float* item  = (const float*)d_in[0];
  const float* pos   = (const float*)d_in[1];
  const float* proto = (const float*)d_in[2];
  const float* w1 = (const float*)d_in[3];
  const float* w2 = (const float*)d_in[4];
  const float* w3 = (const float*)d_in[5];
  const float* w4 = (const float*)d_in[6];
  const float* w5 = (const float*)d_in[7];
  const float* w6 = (const float*)d_in[8];
  const float* w7 = (const float*)d_in[9];
  const float* ln1g = (const float*)d_in[10];
  const float* ln1b = (const float*)d_in[11];
  const float* ln2g = (const float*)d_in[12];
  const float* ln2b = (const float*)d_in[13];
  const float* ln3g = (const float*)d_in[14];
  const float* ln3b = (const float*)d_in[15];
  const float* ln4g = (const float*)d_in[16];
  const float* ln4b = (const float*)d_in[17];
  const int* seq = (const int*)d_in[18];
  float* out = (float*)d_out;

  char* ws = (char*)d_ws;
  float* accum = (float*)ws;
  float* mean  = (float*)(ws + 256);
  unsigned short* finalbf = (unsigned short*)(ws + 1024);
  unsigned short* itembf  = (unsigned short*)(ws + 263168);
  unsigned short* wtbuf   = (unsigned short*)(ws + 25863168);

  wprep<<<4, 256, 0, stream>>>(w1, w3, w4, w6, wtbuf);
  conv_bf16<<<2048, 256, 0, stream>>>(item, itembf, ITEMS * H / 4);

  sine_row<<<BQ, 256, 0, stream>>>(item, pos, proto, w2, w5, w7, wtbuf,
                                   ln1g, ln1b, ln2g, ln2b, ln3g, ln3b, ln4g, ln4b,
                                   seq, finalbf);

  gemm_scores<<<dim3((ITEMS + GBN - 1) / GBN, BQ / GBM), 256, 0, stream>>>(finalbf, itembf, out);

  proto_mean<<<1, 128, 0, stream>>>(proto, mean, accum);
  proto_cov<<<LPROTO, 256, 0, stream>>>(proto, mean, accum);
  lc_final<<<1, 1, 0, stream>>>(accum, out);
}